// Round 7
// baseline (471.985 us; speedup 1.0000x reference)
//
#include <hip/hip_runtime.h>

typedef unsigned short ushort_t;
typedef __attribute__((ext_vector_type(8))) short short8;
typedef __attribute__((ext_vector_type(4))) float f32x4;

struct __align__(4) us2 { unsigned short x, y; };

__device__ __forceinline__ float b2f(unsigned short u) {
    union { unsigned int i; float f; } v; v.i = ((unsigned int)u) << 16; return v.f;
}
__device__ __forceinline__ unsigned short f2b(float f) {
    union { float f; unsigned int i; } v; v.f = f;
    unsigned int r = (v.i + 0x7FFF + ((v.i >> 16) & 1)) >> 16;
    return (unsigned short)r;
}

// ---- edge dtype detection: flags[0] = 1 if edge_index is int64 ----------
// int64 node ids < 2^31  => every odd int32 word is 0. int32 ids: odd words
// are node ids, 512 consecutive all-zero is impossible for random ids.
__global__ void k_detect(const int* __restrict__ ei, int* __restrict__ flags) {
    __shared__ int ornz;
    int t = threadIdx.x;
    if (t == 0) ornz = 0;
    __syncthreads();
    int z = 0;
    for (int i = t; i < 512; i += 256) z |= ei[2 * i + 1];
    atomicOr(&ornz, z);
    __syncthreads();
    if (t == 0) flags[0] = (ornz == 0) ? 1 : 0;
}

__device__ __forceinline__ void load_edge(const int* __restrict__ ei, int e, int E,
                                          int is64, int& s, int& d) {
    if (is64) { s = ei[2 * e]; d = ei[2 * (E + e)]; }   // little-endian low words
    else      { s = ei[e];     d = ei[E + e]; }
}

// ---- CSR build ----------------------------------------------------------

__global__ void k_count(const int* __restrict__ ei, int E, unsigned N,
                        int* __restrict__ cnt, const int* __restrict__ flags) {
    int e = blockIdx.x * 256 + threadIdx.x;
    if (e < E) {
        int s, d; load_edge(ei, e, E, flags[0], s, d);
        if ((unsigned)d < N && (unsigned)s < N) atomicAdd(&cnt[d], 1);
    }
}

__global__ void k_assign(const int* __restrict__ cnt, int N,
                         int* __restrict__ pos, float* __restrict__ dinv,
                         int* __restrict__ cursor) {
    __shared__ int sd[256];
    __shared__ int sbase;
    int t = threadIdx.x;
    int n = blockIdx.x * 256 + t;
    int c = (n < N) ? cnt[n] : 0;
    sd[t] = c;
    for (int o = 1; o < 256; o <<= 1) {
        __syncthreads();
        int v = (t >= o) ? sd[t - o] : 0;
        __syncthreads();
        sd[t] += v;
    }
    __syncthreads();
    if (t == 255) sbase = atomicAdd(cursor, sd[255]);
    __syncthreads();
    if (n < N) {
        pos[n] = sbase + sd[t] - c;     // exclusive offset
        dinv[n] = rsqrtf((float)c + 1.0f);
    }
}

// after this kernel, pos[n] == segment end (start = pos[n] - cnt[n])
__global__ void k_fill(const int* __restrict__ ei, int E, unsigned N,
                       int* __restrict__ pos, int* __restrict__ srcs,
                       const int* __restrict__ flags) {
    int e = blockIdx.x * 256 + threadIdx.x;
    if (e < E) {
        int s, d; load_edge(ei, e, E, flags[0], s, d);
        if ((unsigned)d < N && (unsigned)s < N) {
            int p = atomicAdd(&pos[d], 1);
            srcs[p] = s;
        }
    }
}

// ---- W transpose + cast f32 -> bf16 (tiny, once per launch) -------------

__global__ void k_transpose(const float* __restrict__ W1, const float* __restrict__ W2,
                            ushort_t* __restrict__ WT) {
    const float* src = blockIdx.x ? W2 : W1;
    ushort_t* dst = WT + blockIdx.x * 16384;
    for (int i = threadIdx.x; i < 16384; i += 256) {
        int n = i >> 7, k = i & 127;
        dst[i] = f2b(src[k * 128 + n]);   // WT[n][k] = W[k][n]
    }
}

// ---- GEMM: C[M,128] = A[M,128] @ W[128,128]; A f32, C bf16, fp32 acc ----
// MFMA layout bit-validated against the VALU GEMM (R3 == R4).

__global__ __launch_bounds__(256) void k_gemm(const float* __restrict__ A,
                                              const ushort_t* __restrict__ WT,
                                              ushort_t* __restrict__ C, int M) {
    __shared__ __align__(16) ushort_t sA[64 * 136];   // stride 136: 2-way banks only
    __shared__ __align__(16) ushort_t sW[128 * 136];
    int t = threadIdx.x;
    int row0 = blockIdx.x * 64;

    // stage W^T (bf16): 16384 elems
    #pragma unroll
    for (int it = 0; it < 8; ++it) {
        int flat = (it * 256 + t) * 8;
        int n = flat >> 7, k = flat & 127;
        uint4 v = *(const uint4*)(WT + flat);
        *(uint4*)(&sW[n * 136 + k]) = v;
    }
    // stage A tile: 64 rows x 128, cast f32 -> bf16
    #pragma unroll
    for (int it = 0; it < 4; ++it) {
        int flat = (it * 256 + t) * 8;
        int r = flat >> 7, cc = flat & 127;
        int row = row0 + r; if (row > M - 1) row = M - 1;
        const float* p = A + (size_t)row * 128 + cc;
        float4 f0 = *(const float4*)p;
        float4 f1 = *(const float4*)(p + 4);
        ushort_t tmp[8] __attribute__((aligned(16)));
        tmp[0] = f2b(f0.x); tmp[1] = f2b(f0.y); tmp[2] = f2b(f0.z); tmp[3] = f2b(f0.w);
        tmp[4] = f2b(f1.x); tmp[5] = f2b(f1.y); tmp[6] = f2b(f1.z); tmp[7] = f2b(f1.w);
        *(uint4*)(&sA[r * 136 + cc]) = *(const uint4*)tmp;
    }
    __syncthreads();

    int w = t >> 6, lane = t & 63;
    int m = lane & 15, quad = lane >> 4;

    f32x4 acc[8] = {};
    #pragma unroll
    for (int k0 = 0; k0 < 128; k0 += 32) {
        short8 af = *(const short8*)(&sA[(w * 16 + m) * 136 + k0 + quad * 8]);
        #pragma unroll
        for (int tt = 0; tt < 8; ++tt) {
            short8 bf = *(const short8*)(&sW[(tt * 16 + m) * 136 + k0 + quad * 8]);
            acc[tt] = __builtin_amdgcn_mfma_f32_16x16x32_bf16(af, bf, acc[tt], 0, 0, 0);
        }
    }
    // C/D layout: col = lane&15, row = quad*4 + r  (m89-verified, R3==R4 validated)
    #pragma unroll
    for (int r = 0; r < 4; ++r) {
        int row = row0 + w * 16 + quad * 4 + r;
        if (row < M) {
            #pragma unroll
            for (int tt = 0; tt < 8; ++tt)
                C[(size_t)row * 128 + tt * 16 + m] = f2b(acc[tt][r]);
        }
    }
}

// ---- Aggregation: out[d] = dinv[d]*sum_src(dinv[s]*xt[s]) + dinv[d]^2*xt[d] + b
// xt is bf16 [N,128]; bias f32; out f32. One wave per destination node.

__global__ __launch_bounds__(256) void k_agg(const ushort_t* __restrict__ xt,
                                             const float* __restrict__ bias,
                                             float* __restrict__ out,
                                             const int* __restrict__ pos,
                                             const int* __restrict__ cnts,
                                             const float* __restrict__ dinv,
                                             const int* __restrict__ srcs, int N) {
    int lane = threadIdx.x & 63;
    int d = (blockIdx.x << 2) + (threadIdx.x >> 6);
    if (d >= N) return;
    int cnt = cnts[d];
    int start = pos[d] - cnt;          // pos is segment END after k_fill
    float a0 = 0.f, a1 = 0.f;

    for (int base = 0; base < cnt; base += 64) {
        int n = cnt - base; if (n > 64) n = 64;
        int sv = 0; float wv = 0.f;
        if (lane < n) {
            sv = srcs[start + base + lane];
            wv = dinv[sv];
        }
        int c = 0;
        for (; c + 4 <= n; c += 4) {
            int   s0 = __shfl(sv, c + 0), s1 = __shfl(sv, c + 1);
            int   s2 = __shfl(sv, c + 2), s3 = __shfl(sv, c + 3);
            float w0 = __shfl(wv, c + 0), w1 = __shfl(wv, c + 1);
            float w2 = __shfl(wv, c + 2), w3 = __shfl(wv, c + 3);
            us2 v0 = *(const us2*)(xt + ((size_t)s0 << 7) + (lane << 1));
            us2 v1 = *(const us2*)(xt + ((size_t)s1 << 7) + (lane << 1));
            us2 v2 = *(const us2*)(xt + ((size_t)s2 << 7) + (lane << 1));
            us2 v3 = *(const us2*)(xt + ((size_t)s3 << 7) + (lane << 1));
            a0 += w0 * b2f(v0.x); a1 += w0 * b2f(v0.y);
            a0 += w1 * b2f(v1.x); a1 += w1 * b2f(v1.y);
            a0 += w2 * b2f(v2.x); a1 += w2 * b2f(v2.y);
            a0 += w3 * b2f(v3.x); a1 += w3 * b2f(v3.y);
        }
        for (; c < n; ++c) {
            int s0 = __shfl(sv, c); float w0 = __shfl(wv, c);
            us2 v0 = *(const us2*)(xt + ((size_t)s0 << 7) + (lane << 1));
            a0 += w0 * b2f(v0.x); a1 += w0 * b2f(v0.y);
        }
    }

    float dd = dinv[d];
    us2 vs = *(const us2*)(xt + ((size_t)d << 7) + (lane << 1));
    float2 ob;
    ob.x = dd * a0 + dd * dd * b2f(vs.x) + bias[lane << 1];
    ob.y = dd * a1 + dd * dd * b2f(vs.y) + bias[(lane << 1) + 1];
    *(float2*)(out + ((size_t)d << 7) + (lane << 1)) = ob;
}

// ---- launch -------------------------------------------------------------

extern "C" void kernel_launch(void* const* d_in, const int* in_sizes, int n_in,
                              void* d_out, int out_size, void* d_ws, size_t ws_size,
                              hipStream_t stream) {
    const float* x  = (const float*)d_in[0];   // [N,128] f32
    const int*   ei = (const int*)d_in[1];     // [2,E] int32 (or int64; detected)
    const float* W1 = (const float*)d_in[2];   // [128,128] f32
    const float* b1 = (const float*)d_in[3];   // [128] f32
    const float* W2 = (const float*)d_in[4];
    const float* b2 = (const float*)d_in[5];
    float* out = (float*)d_out;                // [N,128] f32  <-- the round-6 lesson

    const int N = in_sizes[0] / 128;
    const int E = in_sizes[1] / 2;

    // workspace layout (256B-aligned), peak ~33.3 MB
    char* ws = (char*)d_ws;
    size_t o = 0;
    auto take = [&](size_t bytes) { size_t r = o; o = (o + bytes + 255) & ~(size_t)255; return r; };
    size_t o_cnt    = take((size_t)N * 4);
    size_t o_cursor = take(4);
    size_t zero_end = o;                  // memset [0, zero_end)
    size_t o_flags  = take(4);
    size_t o_pos    = take((size_t)N * 4);
    size_t o_dinv   = take((size_t)N * 4);
    size_t o_srcs   = take((size_t)E * 4);
    size_t o_WT     = take(2 * 128 * 128 * 2);
    size_t o_xt     = take((size_t)N * 128 * 2);
    (void)ws_size;

    int*      cnt    = (int*)(ws + o_cnt);
    int*      cursor = (int*)(ws + o_cursor);
    int*      flags  = (int*)(ws + o_flags);
    int*      pos    = (int*)(ws + o_pos);
    float*    dinv   = (float*)(ws + o_dinv);
    int*      srcs   = (int*)(ws + o_srcs);
    ushort_t* WT     = (ushort_t*)(ws + o_WT);
    ushort_t* xt     = (ushort_t*)(ws + o_xt);
    float*    h      = out;               // layer-1 f32 output staged in d_out

    hipMemsetAsync(d_ws, 0, zero_end, stream);

    int gE = (E + 255) / 256;
    int gN = (N + 255) / 256;
    k_detect<<<1, 256, 0, stream>>>(ei, flags);
    k_count<<<gE, 256, 0, stream>>>(ei, E, (unsigned)N, cnt, flags);
    k_assign<<<gN, 256, 0, stream>>>(cnt, N, pos, dinv, cursor);
    k_fill<<<gE, 256, 0, stream>>>(ei, E, (unsigned)N, pos, srcs, flags);
    k_transpose<<<2, 256, 0, stream>>>(W1, W2, WT);

    int gG = (N + 63) / 64;
    int gA = (N + 3) / 4;
    // layer 1: xt = bf16(x @ W1); h = agg(xt) + b1  (h f32, in d_out)
    k_gemm<<<gG, 256, 0, stream>>>(x, WT, xt, N);
    k_agg<<<gA, 256, 0, stream>>>(xt, b1, h, pos, cnt, dinv, srcs, N);
    // layer 2: xt = bf16(h @ W2); out = agg(xt) + b2  (f32)
    k_gemm<<<gG, 256, 0, stream>>>(h, WT + 16384, xt, N);
    k_agg<<<gA, 256, 0, stream>>>(xt, b2, out, pos, cnt, dinv, srcs, N);
}

// Round 8
// 393.032 us; speedup vs baseline: 1.2009x; 1.2009x over previous
//
#include <hip/hip_runtime.h>

typedef unsigned short ushort_t;
typedef __attribute__((ext_vector_type(8))) short short8;
typedef __attribute__((ext_vector_type(4))) float f32x4;

struct __align__(4) us2 { unsigned short x, y; };
struct __align__(8) us4 { unsigned short x, y, z, w; };

__device__ __forceinline__ float b2f(unsigned short u) {
    union { unsigned int i; float f; } v; v.i = ((unsigned int)u) << 16; return v.f;
}
__device__ __forceinline__ unsigned short f2b(float f) {
    union { float f; unsigned int i; } v; v.f = f;
    unsigned int r = (v.i + 0x7FFF + ((v.i >> 16) & 1)) >> 16;
    return (unsigned short)r;
}

// ---- edge dtype detection: flags[0] = 1 if edge_index is int64 ----------
__global__ void k_detect(const int* __restrict__ ei, int* __restrict__ flags) {
    __shared__ int ornz;
    int t = threadIdx.x;
    if (t == 0) ornz = 0;
    __syncthreads();
    int z = 0;
    for (int i = t; i < 512; i += 256) z |= ei[2 * i + 1];
    atomicOr(&ornz, z);
    __syncthreads();
    if (t == 0) flags[0] = (ornz == 0) ? 1 : 0;
}

__device__ __forceinline__ void load_edge(const int* __restrict__ ei, int e, int E,
                                          int is64, int& s, int& d) {
    if (is64) { s = ei[2 * e]; d = ei[2 * (E + e)]; }   // little-endian low words
    else      { s = ei[e];     d = ei[E + e]; }
}

// ---- bucket histogram: bhist[d >> BSH]++ over all edges -----------------
__global__ void k_hist(const int* __restrict__ ei, int E, unsigned N,
                       const int* __restrict__ flags, int* __restrict__ bhist,
                       int BSH, int NB) {
    __shared__ int lh[256];
    int t = threadIdx.x;
    for (int b = t; b < NB; b += 256) lh[b] = 0;
    __syncthreads();
    int e0 = blockIdx.x * 4096;
    int is64 = flags[0];
    #pragma unroll
    for (int i = 0; i < 16; ++i) {
        int e = e0 + i * 256 + t;
        if (e < E) {
            int s, d; load_edge(ei, e, E, is64, s, d);
            if ((unsigned)s < N && (unsigned)d < N) atomicAdd(&lh[d >> BSH], 1);
        }
    }
    __syncthreads();
    for (int b = t; b < NB; b += 256) { int v = lh[b]; if (v) atomicAdd(&bhist[b], v); }
}

// ---- exclusive scan of bucket hist (NB <= 256), one block ---------------
__global__ void k_scanb(const int* __restrict__ bhist, int NB,
                        int* __restrict__ bkbase, int* __restrict__ bkcur) {
    __shared__ int sd[256];
    int t = threadIdx.x;
    int v0 = (t < NB) ? bhist[t] : 0;
    sd[t] = v0;
    for (int o = 1; o < 256; o <<= 1) {
        __syncthreads();
        int v = (t >= o) ? sd[t - o] : 0;
        __syncthreads();
        sd[t] += v;
    }
    __syncthreads();
    if (t < NB) { int ex = sd[t] - v0; bkbase[t] = ex; bkcur[t] = ex; }
}

// ---- bucket scatter: edges -> (bs, bd) grouped by destination bucket ----
__global__ __launch_bounds__(256) void k_bucket(const int* __restrict__ ei, int E, unsigned N,
                                                const int* __restrict__ flags,
                                                int* __restrict__ bkcur,
                                                int* __restrict__ bs, int* __restrict__ bd,
                                                int BSH, int NB) {
    __shared__ int lss[4096];
    __shared__ int ldd[4096];
    __shared__ int lhist[256];
    __shared__ int lcur[256];
    int t = threadIdx.x;
    int e0 = blockIdx.x * 4096;
    int is64 = flags[0];
    for (int b = t; b < NB; b += 256) lhist[b] = 0;
    __syncthreads();
    #pragma unroll
    for (int i = 0; i < 16; ++i) {
        int idx = i * 256 + t, e = e0 + idx;
        int s = -1, d = -1;
        if (e < E) {
            load_edge(ei, e, E, is64, s, d);
            if (!((unsigned)s < N && (unsigned)d < N)) d = -1;
        }
        lss[idx] = s; ldd[idx] = d;
        if (d >= 0) atomicAdd(&lhist[d >> BSH], 1);
    }
    __syncthreads();
    for (int b = t; b < NB; b += 256) {
        int v = lhist[b];
        lcur[b] = v ? atomicAdd(&bkcur[b], v) : 0;
    }
    __syncthreads();
    #pragma unroll
    for (int i = 0; i < 16; ++i) {
        int idx = i * 256 + t;
        int d = ldd[idx];
        if (d >= 0) {
            int p = atomicAdd(&lcur[d >> BSH], 1);
            bs[p] = lss[idx]; bd[p] = d;
        }
    }
}

// ---- per-bucket degree count (LDS counters, coalesced cnt write) --------
__global__ void k_count2(const int* __restrict__ bd, const int* __restrict__ bkbase,
                         const int* __restrict__ bkcur, int N, int BSH,
                         int* __restrict__ cnt) {
    __shared__ int lc[512];
    int b = blockIdx.x, t = threadIdx.x;
    int nbase = b << BSH;
    int nn = min(1 << BSH, N - nbase);
    for (int j = t; j < nn; j += 256) lc[j] = 0;
    __syncthreads();
    int s0 = bkbase[b], s1 = bkcur[b];
    for (int i = s0 + t; i < s1; i += 256) atomicAdd(&lc[bd[i] - nbase], 1);
    __syncthreads();
    for (int j = t; j < nn; j += 256) cnt[nbase + j] = lc[j];
}

// ---- global exclusive scan of cnt -> pos (start); dinv ------------------
__global__ void k_assign(const int* __restrict__ cnt, int N,
                         int* __restrict__ pos, float* __restrict__ dinv,
                         int* __restrict__ cursor) {
    __shared__ int sd[256];
    __shared__ int sbase;
    int t = threadIdx.x;
    int n = blockIdx.x * 256 + t;
    int c = (n < N) ? cnt[n] : 0;
    sd[t] = c;
    for (int o = 1; o < 256; o <<= 1) {
        __syncthreads();
        int v = (t >= o) ? sd[t - o] : 0;
        __syncthreads();
        sd[t] += v;
    }
    __syncthreads();
    if (t == 255) sbase = atomicAdd(cursor, sd[255]);
    __syncthreads();
    if (n < N) {
        pos[n] = sbase + sd[t] - c;     // exclusive start (never mutated again)
        dinv[n] = rsqrtf((float)c + 1.0f);
    }
}

// ---- per-bucket CSR fill (LDS cursors, L2-local srcs writes) ------------
__global__ void k_fill2(const int* __restrict__ bs, const int* __restrict__ bd,
                        const int* __restrict__ bkbase, const int* __restrict__ bkcur,
                        const int* __restrict__ pos, int N, int BSH,
                        int* __restrict__ srcs) {
    __shared__ int lcur[512];
    int b = blockIdx.x, t = threadIdx.x;
    int nbase = b << BSH;
    int nn = min(1 << BSH, N - nbase);
    for (int j = t; j < nn; j += 256) lcur[j] = pos[nbase + j];
    __syncthreads();
    int s0 = bkbase[b], s1 = bkcur[b];
    for (int i = s0 + t; i < s1; i += 256) {
        int d = bd[i];
        int p = atomicAdd(&lcur[d - nbase], 1);
        srcs[p] = bs[i];
    }
}

// ---- W transpose + cast f32 -> bf16 -------------------------------------
__global__ void k_transpose(const float* __restrict__ W1, const float* __restrict__ W2,
                            ushort_t* __restrict__ WT) {
    const float* src = blockIdx.x ? W2 : W1;
    ushort_t* dst = WT + blockIdx.x * 16384;
    for (int i = threadIdx.x; i < 16384; i += 256) {
        int n = i >> 7, k = i & 127;
        dst[i] = f2b(src[k * 128 + n]);   // WT[n][k] = W[k][n]
    }
}

// ---- GEMM: C[M,128] = A[M,128] @ W[128,128]; A f32, C bf16, fp32 acc ----
__global__ __launch_bounds__(256) void k_gemm(const float* __restrict__ A,
                                              const ushort_t* __restrict__ WT,
                                              ushort_t* __restrict__ C, int M) {
    __shared__ __align__(16) ushort_t sA[64 * 136];
    __shared__ __align__(16) ushort_t sW[128 * 136];
    int t = threadIdx.x;
    int row0 = blockIdx.x * 64;

    #pragma unroll
    for (int it = 0; it < 8; ++it) {
        int flat = (it * 256 + t) * 8;
        int n = flat >> 7, k = flat & 127;
        uint4 v = *(const uint4*)(WT + flat);
        *(uint4*)(&sW[n * 136 + k]) = v;
    }
    #pragma unroll
    for (int it = 0; it < 4; ++it) {
        int flat = (it * 256 + t) * 8;
        int r = flat >> 7, cc = flat & 127;
        int row = row0 + r; if (row > M - 1) row = M - 1;
        const float* p = A + (size_t)row * 128 + cc;
        float4 f0 = *(const float4*)p;
        float4 f1 = *(const float4*)(p + 4);
        ushort_t tmp[8] __attribute__((aligned(16)));
        tmp[0] = f2b(f0.x); tmp[1] = f2b(f0.y); tmp[2] = f2b(f0.z); tmp[3] = f2b(f0.w);
        tmp[4] = f2b(f1.x); tmp[5] = f2b(f1.y); tmp[6] = f2b(f1.z); tmp[7] = f2b(f1.w);
        *(uint4*)(&sA[r * 136 + cc]) = *(const uint4*)tmp;
    }
    __syncthreads();

    int w = t >> 6, lane = t & 63;
    int m = lane & 15, quad = lane >> 4;

    f32x4 acc[8] = {};
    #pragma unroll
    for (int k0 = 0; k0 < 128; k0 += 32) {
        short8 af = *(const short8*)(&sA[(w * 16 + m) * 136 + k0 + quad * 8]);
        #pragma unroll
        for (int tt = 0; tt < 8; ++tt) {
            short8 bf = *(const short8*)(&sW[(tt * 16 + m) * 136 + k0 + quad * 8]);
            acc[tt] = __builtin_amdgcn_mfma_f32_16x16x32_bf16(af, bf, acc[tt], 0, 0, 0);
        }
    }
    #pragma unroll
    for (int r = 0; r < 4; ++r) {
        int row = row0 + w * 16 + quad * 4 + r;
        if (row < M) {
            #pragma unroll
            for (int tt = 0; tt < 8; ++tt)
                C[(size_t)row * 128 + tt * 16 + m] = f2b(acc[tt][r]);
        }
    }
}

// ---- Aggregation: out[d] = dinv[d]*sum(dinv[s]*xt[s]) + dinv[d]^2*xt[d] + b
// Wave per destination; 2 edge-slots x 32 lanes x us4 (4 features, 8B).
__global__ __launch_bounds__(256) void k_agg(const ushort_t* __restrict__ xt,
                                             const float* __restrict__ bias,
                                             float* __restrict__ out,
                                             const int* __restrict__ pos,
                                             const int* __restrict__ cnts,
                                             const float* __restrict__ dinv,
                                             const int* __restrict__ srcs, int N) {
    int lane = threadIdx.x & 63;
    int slot = lane >> 5, j = lane & 31;
    int d = (blockIdx.x << 2) + (threadIdx.x >> 6);
    if (d >= N) return;
    int cn = cnts[d];
    int start = pos[d];
    float a0 = 0.f, a1 = 0.f, a2 = 0.f, a3 = 0.f;

    for (int base = 0; base < cn; base += 64) {
        int n = cn - base; if (n > 64) n = 64;
        int sv = 0; float wv = 0.f;
        if (lane < n) {
            sv = srcs[start + base + lane];
            wv = dinv[sv];
        }
        #pragma unroll 4
        for (int c = 0; c < n; c += 2) {
            int ce = c + slot;
            int cc = min(ce, n - 1);
            int s = __shfl(sv, cc);
            float w = __shfl(wv, cc);
            if (ce >= n) w = 0.f;
            us4 v = *(const us4*)(xt + ((size_t)s << 7) + (j << 2));
            a0 += w * b2f(v.x); a1 += w * b2f(v.y);
            a2 += w * b2f(v.z); a3 += w * b2f(v.w);
        }
    }
    // combine the two edge-slots: lanes (j, j+32) hold the same features
    a0 += __shfl_xor(a0, 32);
    a1 += __shfl_xor(a1, 32);
    a2 += __shfl_xor(a2, 32);
    a3 += __shfl_xor(a3, 32);

    if (slot == 0) {
        float dd = dinv[d];
        us4 vs = *(const us4*)(xt + ((size_t)d << 7) + (j << 2));
        float4 bb = *(const float4*)(bias + (j << 2));
        float4 ob;
        ob.x = dd * a0 + dd * dd * b2f(vs.x) + bb.x;
        ob.y = dd * a1 + dd * dd * b2f(vs.y) + bb.y;
        ob.z = dd * a2 + dd * dd * b2f(vs.z) + bb.z;
        ob.w = dd * a3 + dd * dd * b2f(vs.w) + bb.w;
        *(float4*)(out + ((size_t)d << 7) + (j << 2)) = ob;
    }
}

// ---- launch -------------------------------------------------------------

extern "C" void kernel_launch(void* const* d_in, const int* in_sizes, int n_in,
                              void* d_out, int out_size, void* d_ws, size_t ws_size,
                              hipStream_t stream) {
    const float* x  = (const float*)d_in[0];   // [N,128] f32
    const int*   ei = (const int*)d_in[1];     // [2,E] int32/int64 (detected)
    const float* W1 = (const float*)d_in[2];   // [128,128] f32
    const float* b1 = (const float*)d_in[3];   // [128] f32
    const float* W2 = (const float*)d_in[4];
    const float* b2 = (const float*)d_in[5];
    float* out = (float*)d_out;                // [N,128] f32

    const int N = in_sizes[0] / 128;
    const int E = in_sizes[1] / 2;

    // bucket size 2^BSH nodes, NB <= 256 buckets (N=100000 -> BSH=9, NB=196)
    int BSH = 9;
    int NB = (N + (1 << BSH) - 1) >> BSH;
    while (NB > 256) { BSH++; NB = (N + (1 << BSH) - 1) >> BSH; }

    // workspace (256B-aligned); bs/bd overlap xt (disjoint lifetimes) ~33.5 MB peak
    char* ws = (char*)d_ws;
    size_t o = 0;
    auto take = [&](size_t bytes) { size_t r = o; o = (o + bytes + 255) & ~(size_t)255; return r; };
    size_t o_bhist  = take(256 * 4);
    size_t o_cursor = take(4);
    size_t zero_end = o;                  // memset [0, zero_end): bhist + cursor
    size_t o_flags  = take(4);
    size_t o_bkbase = take(256 * 4);
    size_t o_bkcur  = take(256 * 4);
    size_t o_cnt    = take((size_t)N * 4);
    size_t o_pos    = take((size_t)N * 4);
    size_t o_dinv   = take((size_t)N * 4);
    size_t o_srcs   = take((size_t)E * 4);
    size_t o_WT     = take(2 * 128 * 128 * 2);
    size_t big_sz   = (size_t)E * 8 > (size_t)N * 256 ? (size_t)E * 8 : (size_t)N * 256;
    size_t o_big    = take(big_sz);
    (void)ws_size;

    int*      bhist  = (int*)(ws + o_bhist);
    int*      cursor = (int*)(ws + o_cursor);
    int*      flags  = (int*)(ws + o_flags);
    int*      bkbase = (int*)(ws + o_bkbase);
    int*      bkcur  = (int*)(ws + o_bkcur);
    int*      cnt    = (int*)(ws + o_cnt);
    int*      pos    = (int*)(ws + o_pos);
    float*    dinv   = (float*)(ws + o_dinv);
    int*      srcs   = (int*)(ws + o_srcs);
    ushort_t* WT     = (ushort_t*)(ws + o_WT);
    int*      bs     = (int*)(ws + o_big);           // CSR-build phase only
    int*      bd     = (int*)(ws + o_big) + E;
    ushort_t* xt     = (ushort_t*)(ws + o_big);      // GEMM phase (after fill2)
    float*    h      = out;                          // layer-1 f32 staged in d_out

    hipMemsetAsync(d_ws, 0, zero_end, stream);

    int gE = (E + 4095) / 4096;
    int gN = (N + 255) / 256;
    k_detect<<<1, 256, 0, stream>>>(ei, flags);
    k_hist<<<gE, 256, 0, stream>>>(ei, E, (unsigned)N, flags, bhist, BSH, NB);
    k_scanb<<<1, 256, 0, stream>>>(bhist, NB, bkbase, bkcur);
    k_bucket<<<gE, 256, 0, stream>>>(ei, E, (unsigned)N, flags, bkcur, bs, bd, BSH, NB);
    k_count2<<<NB, 256, 0, stream>>>(bd, bkbase, bkcur, N, BSH, cnt);
    k_assign<<<gN, 256, 0, stream>>>(cnt, N, pos, dinv, cursor);
    k_fill2<<<NB, 256, 0, stream>>>(bs, bd, bkbase, bkcur, pos, N, BSH, srcs);
    k_transpose<<<2, 256, 0, stream>>>(W1, W2, WT);

    int gG = (N + 63) / 64;
    int gA = (N + 3) / 4;
    // layer 1: xt = bf16(x @ W1); h = agg(xt) + b1   (xt overwrites bs/bd - done)
    k_gemm<<<gG, 256, 0, stream>>>(x, WT, xt, N);
    k_agg<<<gA, 256, 0, stream>>>(xt, b1, h, pos, cnt, dinv, srcs, N);
    // layer 2: xt = bf16(h @ W2); out = agg(xt) + b2
    k_gemm<<<gG, 256, 0, stream>>>(h, WT + 16384, xt, N);
    k_agg<<<gA, 256, 0, stream>>>(xt, b2, out, pos, cnt, dinv, srcs, N);
}